// Round 3
// baseline (264.885 us; speedup 1.0000x reference)
//
#include <hip/hip_runtime.h>

// B=8, S=2048, IN=1024, H=1024
//   q  = vec @ wq_w^T + wq_b            [B,S,H]
//   ret= relu(q_b^T q_b) per batch      [B,H,H]   (registers only)
//   out= ret @ lin_w + lin_b            [B,H]
//
// Pipeline: cvt_wq+init ; cvt_vec ; gemm_q (m97-style LDS) -> qT bf16 ;
//           syrk_dot: BARRIER-FREE, LDS-FREE — MFMA fragments loaded directly
//           from L2 via global_load_dwordx4 (frag = 16B/lane, row-contiguous).

#define BM 128
#define BN 128

typedef short     bf16x8 __attribute__((ext_vector_type(8)));
typedef unsigned short u16x8 __attribute__((ext_vector_type(8)));
typedef float     f32x4 __attribute__((ext_vector_type(4)));

__device__ inline unsigned short f2bf(float f) {
  unsigned int u = __float_as_uint(f);
  u += 0x7fffu + ((u >> 16) & 1u);   // RNE
  return (unsigned short)(u >> 16);
}

__device__ inline u16x8 pack8(float4 a, float4 b) {
  u16x8 r;
  r[0] = f2bf(a.x); r[1] = f2bf(a.y); r[2] = f2bf(a.z); r[3] = f2bf(a.w);
  r[4] = f2bf(b.x); r[5] = f2bf(b.y); r[6] = f2bf(b.z); r[7] = f2bf(b.w);
  return r;
}

__device__ inline void async16(unsigned short* lds, const unsigned short* g) {
  __builtin_amdgcn_global_load_lds(
      (const __attribute__((address_space(1))) void*)g,
      (__attribute__((address_space(3))) void*)lds,
      16, 0, 0);
}

// wq fp32->bf16 (131072 x8-groups) + out init (8192), one launch
__global__ __launch_bounds__(256) void cvt_wq_init(
    const float* __restrict__ wq, unsigned short* __restrict__ wqbf,
    const float* __restrict__ lin_b, float* __restrict__ out)
{
  int i = blockIdx.x * 256 + threadIdx.x;
  if (i < 131072) {
    const float4* s = (const float4*)(wq + (size_t)i * 8);
    float4 a = s[0], b = s[1];
    *(u16x8*)(wqbf + (size_t)i * 8) = pack8(a, b);
  }
  if (i < 8192) out[i] = lin_b[0];
}

// vec fp32 -> bf16, 8 elements/thread
__global__ __launch_bounds__(256) void cvt_bf16(
    const float* __restrict__ src, unsigned short* __restrict__ dst, int n8)
{
  int i = blockIdx.x * 256 + threadIdx.x;
  if (i < n8) {
    const float4* s = (const float4*)(src + (size_t)i * 8);
    float4 a = s[0], b = s[1];
    *(u16x8*)(dst + (size_t)i * 8) = pack8(a, b);
  }
}

// ---------------- gemm_q (m97-style): qT = wqbf * vecbf^T + bias ----------------
__global__ __launch_bounds__(256) void gemm_q(
    const unsigned short* __restrict__ A, const unsigned short* __restrict__ Bm,
    const float* __restrict__ bias, unsigned short* __restrict__ qT)
{
  __shared__ unsigned short As[BM * 32];
  __shared__ unsigned short Bs[BN * 32];

  const int m0 = blockIdx.y * BM;
  const int n0 = blockIdx.x * BN;
  const int t    = threadIdx.x;
  const int lane = t & 63;
  const int wave = t >> 6;
  const int wm = (wave >> 1) * 64;
  const int wn = (wave & 1) * 64;
  const int quad = lane >> 4;
  const int lrow = lane & 15;

  const int srow = t >> 2;                               // 0..63
  const int gcol = (((t & 3) ^ ((srow >> 1) & 3)) << 3); // swizzled col (shorts)
  const unsigned short* gA0 = A  + (size_t)(m0 + srow) * 1024 + gcol;
  const unsigned short* gA1 = gA0 + (size_t)64 * 1024;
  const unsigned short* gB0 = Bm + (size_t)(n0 + srow) * 1024 + gcol;
  const unsigned short* gB1 = gB0 + (size_t)64 * 1024;

  const int rc = (quad ^ ((lrow >> 1) & 3)) << 3;        // shorts

  f32x4 acc[4][4];
#pragma unroll
  for (int i = 0; i < 4; ++i)
#pragma unroll
    for (int j = 0; j < 4; ++j) acc[i][j] = (f32x4){0.f, 0.f, 0.f, 0.f};

  for (int k0 = 0; k0 < 1024; k0 += 32) {
    async16(&As[t * 8],        gA0 + k0);
    async16(&As[2048 + t * 8], gA1 + k0);
    async16(&Bs[t * 8],        gB0 + k0);
    async16(&Bs[2048 + t * 8], gB1 + k0);
    __syncthreads();

    bf16x8 af[4], bfr[4];
#pragma unroll
    for (int i = 0; i < 4; ++i)
      af[i] = *(const bf16x8*)&As[(wm + i * 16 + lrow) * 32 + rc];
#pragma unroll
    for (int j = 0; j < 4; ++j)
      bfr[j] = *(const bf16x8*)&Bs[(wn + j * 16 + lrow) * 32 + rc];
#pragma unroll
    for (int i = 0; i < 4; ++i)
#pragma unroll
      for (int j = 0; j < 4; ++j)
        acc[i][j] = __builtin_amdgcn_mfma_f32_16x16x32_bf16(af[i], bfr[j], acc[i][j], 0, 0, 0);
    __syncthreads();
  }

#pragma unroll
  for (int i = 0; i < 4; ++i) {
    const int mb = m0 + wm + i * 16 + quad * 4;
#pragma unroll
    for (int r = 0; r < 4; ++r) {
      const float bv = bias[mb + r];
#pragma unroll
      for (int j = 0; j < 4; ++j) {
        const int n = n0 + wn + j * 16 + lrow;
        qT[(size_t)(mb + r) * 16384 + n] = f2bf(acc[i][j][r] + bv);
      }
    }
  }
}

// ------- fallback gemm_q (fused fp32->bf16 inline), used if ws too small -------
__global__ __launch_bounds__(256) void gemm_q_fused(
    const float* __restrict__ Wq, const float* __restrict__ V,
    const float* __restrict__ bias, unsigned short* __restrict__ qT)
{
  __shared__ unsigned short As[BM * 32];
  __shared__ unsigned short Bs[BN * 32];

  const int m0 = blockIdx.y * BM;
  const int n0 = blockIdx.x * BN;
  const int t    = threadIdx.x;
  const int lane = t & 63;
  const int wave = t >> 6;
  const int wm = (wave >> 1) * 64;
  const int wn = (wave & 1) * 64;
  const int quad = lane >> 4;
  const int lrow = lane & 15;

  const int sr = t >> 1;
  const int sc = (t & 1) << 4;
  const float* gA = Wq + (size_t)(m0 + sr) * 1024 + sc;
  const float* gB = V  + (size_t)(n0 + sr) * 1024 + sc;

  f32x4 acc[4][4];
#pragma unroll
  for (int i = 0; i < 4; ++i)
#pragma unroll
    for (int j = 0; j < 4; ++j) acc[i][j] = (f32x4){0.f, 0.f, 0.f, 0.f};

  for (int k0 = 0; k0 < 1024; k0 += 32) {
    const float4* a4 = (const float4*)(gA + k0);
    const float4* b4 = (const float4*)(gB + k0);
    float4 av0 = a4[0], av1 = a4[1], av2 = a4[2], av3 = a4[3];
    float4 bv0 = b4[0], bv1 = b4[1], bv2 = b4[2], bv3 = b4[3];
    *(u16x8*)&As[sr * 32 + sc]     = pack8(av0, av1);
    *(u16x8*)&As[sr * 32 + sc + 8] = pack8(av2, av3);
    *(u16x8*)&Bs[sr * 32 + sc]     = pack8(bv0, bv1);
    *(u16x8*)&Bs[sr * 32 + sc + 8] = pack8(bv2, bv3);
    __syncthreads();

    bf16x8 af[4], bfr[4];
#pragma unroll
    for (int i = 0; i < 4; ++i)
      af[i] = *(const bf16x8*)&As[(wm + i * 16 + lrow) * 32 + quad * 8];
#pragma unroll
    for (int j = 0; j < 4; ++j)
      bfr[j] = *(const bf16x8*)&Bs[(wn + j * 16 + lrow) * 32 + quad * 8];
#pragma unroll
    for (int i = 0; i < 4; ++i)
#pragma unroll
      for (int j = 0; j < 4; ++j)
        acc[i][j] = __builtin_amdgcn_mfma_f32_16x16x32_bf16(af[i], bfr[j], acc[i][j], 0, 0, 0);
    __syncthreads();
  }

#pragma unroll
  for (int i = 0; i < 4; ++i) {
    const int mb = m0 + wm + i * 16 + quad * 4;
#pragma unroll
    for (int r = 0; r < 4; ++r) {
      const float bv = bias[mb + r];
#pragma unroll
      for (int j = 0; j < 4; ++j) {
        const int n = n0 + wn + j * 16 + lrow;
        qT[(size_t)(mb + r) * 16384 + n] = f2bf(acc[i][j][r] + bv);
      }
    }
  }
}

// ---------------- syrk_dot: barrier-free, LDS-free, direct-from-L2 ----------------
// Per batch C = qb qb^T; A/B fragments (16B/lane, row-contiguous) loaded straight
// from qT with global_load_dwordx4; no __syncthreads in the K-loop at all.
__global__ __launch_bounds__(256) void syrk_dot(
    const unsigned short* __restrict__ qT, const float* __restrict__ W,
    float* __restrict__ out)
{
  const int bb = blockIdx.z;
  const int x0 = blockIdx.y * BM;
  const int y0 = blockIdx.x * BN;
  const int t    = threadIdx.x;
  const int lane = t & 63;
  const int wave = t >> 6;
  const int wm = (wave >> 1) * 64;
  const int wn = (wave & 1) * 64;
  const int quad = lane >> 4;
  const int lrow = lane & 15;

  // fragment row pointers: lane covers qT row (tile_row + lrow), K chunk quad*8
  const size_t kbase = (size_t)bb * 2048 + quad * 8;
  const unsigned short* pA[4];
  const unsigned short* pB[4];
#pragma unroll
  for (int i = 0; i < 4; ++i) {
    pA[i] = qT + (size_t)(x0 + wm + i * 16 + lrow) * 16384 + kbase;
    pB[i] = qT + (size_t)(y0 + wn + i * 16 + lrow) * 16384 + kbase;
  }

  f32x4 acc[4][4];
#pragma unroll
  for (int i = 0; i < 4; ++i)
#pragma unroll
    for (int j = 0; j < 4; ++j) acc[i][j] = (f32x4){0.f, 0.f, 0.f, 0.f};

  for (int k0 = 0; k0 < 2048; k0 += 32) {
    bf16x8 af[4], bfr[4];
#pragma unroll
    for (int i = 0; i < 4; ++i) af[i]  = *(const bf16x8*)(pA[i] + k0);
#pragma unroll
    for (int j = 0; j < 4; ++j) bfr[j] = *(const bf16x8*)(pB[j] + k0);
#pragma unroll
    for (int i = 0; i < 4; ++i)
#pragma unroll
      for (int j = 0; j < 4; ++j)
        acc[i][j] = __builtin_amdgcn_mfma_f32_16x16x32_bf16(af[i], bfr[j], acc[i][j], 0, 0, 0);
  }

  // epilogue: out[bb, x] += sum_y relu(C[x][y]) * W[y]
  float wv[4];
#pragma unroll
  for (int j = 0; j < 4; ++j) wv[j] = W[y0 + wn + j * 16 + lrow];

#pragma unroll
  for (int i = 0; i < 4; ++i) {
#pragma unroll
    for (int r = 0; r < 4; ++r) {
      float p = 0.f;
#pragma unroll
      for (int j = 0; j < 4; ++j) {
        float v = acc[i][j][r];
        v = v > 0.f ? v : 0.f;
        p += v * wv[j];
      }
#pragma unroll
      for (int off = 1; off < 16; off <<= 1) p += __shfl_xor(p, off, 64);
      if (lrow == 0) {
        const int x = x0 + wm + i * 16 + quad * 4 + r;
        atomicAdd(&out[bb * 1024 + x], p);
      }
    }
  }
}

extern "C" void kernel_launch(void* const* d_in, const int* in_sizes, int n_in,
                              void* d_out, int out_size, void* d_ws, size_t ws_size,
                              hipStream_t stream) {
  const float* vec   = (const float*)d_in[0];  // [8,2048,1024]
  const float* wq_w  = (const float*)d_in[1];  // [1024,1024]
  const float* wq_b  = (const float*)d_in[2];  // [1024]
  const float* lin_w = (const float*)d_in[3];  // [1,1024]
  const float* lin_b = (const float*)d_in[4];  // [1]
  float* out = (float*)d_out;                  // [8,1024]

  unsigned short* qT = (unsigned short*)d_ws;                    // 32 MiB
  const size_t need = (size_t)(32 + 32 + 2) * 1024 * 1024;

  if (ws_size >= need) {
    unsigned short* vecbf = qT + (size_t)16 * 1024 * 1024;       // 32 MiB
    unsigned short* wqbf  = vecbf + (size_t)16 * 1024 * 1024;    // 2 MiB
    cvt_wq_init<<<dim3(512), dim3(256), 0, stream>>>(wq_w, wqbf, lin_b, out);
    cvt_bf16<<<dim3(8192), dim3(256), 0, stream>>>(vec, vecbf, 16777216 / 8);
    gemm_q<<<dim3(128, 8), dim3(256), 0, stream>>>(wqbf, vecbf, wq_b, qT);
  } else {
    // still need out initialized
    cvt_wq_init<<<dim3(512), dim3(256), 0, stream>>>(wq_w, qT /*scratch unused ok? no: write below*/, lin_b, out);
    gemm_q_fused<<<dim3(128, 8), dim3(256), 0, stream>>>(wq_w, vec, wq_b, qT);
  }
  syrk_dot<<<dim3(8, 8, 8), dim3(256), 0, stream>>>(qT, lin_w, out);
}

// Round 4
// 186.559 us; speedup vs baseline: 1.4198x; 1.4198x over previous
//
#include <hip/hip_runtime.h>

// B=8, S=2048, IN=1024, H=1024
//   q  = vec @ wq_w^T + wq_b            [B,S,H]
//   ret= relu(q_b^T q_b) per batch      [B,H,H]   (registers only)
//   out= ret @ lin_w + lin_b            [B,H]
//
// Pipeline: prep (out-init + wq/vec fp32->bf16, one launch)
//           gemm_q (m97-style global_load_lds, swizzled LDS) -> qT bf16
//           syrk_dot: SYMMETRIC — only ty<=tx tiles (36/64 of work); off-diag
//           tiles emit both row (out[x]+=relu*W[y]) and col (out[y]+=relu*W[x])
//           contributions from the same accumulators. LDS BK=64, swizzled.

#define BM 128
#define BN 128

typedef short     bf16x8 __attribute__((ext_vector_type(8)));
typedef unsigned short u16x8 __attribute__((ext_vector_type(8)));
typedef float     f32x4 __attribute__((ext_vector_type(4)));

__device__ inline unsigned short f2bf(float f) {
  unsigned int u = __float_as_uint(f);
  u += 0x7fffu + ((u >> 16) & 1u);   // RNE
  return (unsigned short)(u >> 16);
}

__device__ inline u16x8 pack8(float4 a, float4 b) {
  u16x8 r;
  r[0] = f2bf(a.x); r[1] = f2bf(a.y); r[2] = f2bf(a.z); r[3] = f2bf(a.w);
  r[4] = f2bf(b.x); r[5] = f2bf(b.y); r[6] = f2bf(b.z); r[7] = f2bf(b.w);
  return r;
}

__device__ inline void async16(unsigned short* lds, const unsigned short* g) {
  __builtin_amdgcn_global_load_lds(
      (const __attribute__((address_space(1))) void*)g,
      (__attribute__((address_space(3))) void*)lds,
      16, 0, 0);
}

// One launch: out init (8192), vec cvt (blocks 0..8191), wq cvt (blocks 8192..8703)
__global__ __launch_bounds__(256) void prep(
    const float* __restrict__ vec, unsigned short* __restrict__ vecbf,
    const float* __restrict__ wq,  unsigned short* __restrict__ wqbf,
    const float* __restrict__ lin_b, float* __restrict__ out)
{
  const int gid = blockIdx.x * 256 + threadIdx.x;
  if (blockIdx.x < 8192) {
    const float4* s = (const float4*)(vec + (size_t)gid * 8);
    float4 a = s[0], b = s[1];
    *(u16x8*)(vecbf + (size_t)gid * 8) = pack8(a, b);
    if (gid < 8192) out[gid] = lin_b[0];
  } else {
    const int i = gid - 8192 * 256;   // 0..131071
    const float4* s = (const float4*)(wq + (size_t)i * 8);
    float4 a = s[0], b = s[1];
    *(u16x8*)(wqbf + (size_t)i * 8) = pack8(a, b);
  }
}

__global__ void init_out(float* __restrict__ out, const float* __restrict__ lin_b) {
  int i = blockIdx.x * 256 + threadIdx.x;
  if (i < 8192) out[i] = lin_b[0];
}

// ---------------- gemm_q (m97-style): qT = wqbf * vecbf^T + bias ----------------
__global__ __launch_bounds__(256) void gemm_q(
    const unsigned short* __restrict__ A, const unsigned short* __restrict__ Bm,
    const float* __restrict__ bias, unsigned short* __restrict__ qT)
{
  __shared__ unsigned short As[BM * 32];
  __shared__ unsigned short Bs[BN * 32];

  const int m0 = blockIdx.y * BM;
  const int n0 = blockIdx.x * BN;
  const int t    = threadIdx.x;
  const int lane = t & 63;
  const int wave = t >> 6;
  const int wm = (wave >> 1) * 64;
  const int wn = (wave & 1) * 64;
  const int quad = lane >> 4;
  const int lrow = lane & 15;

  const int srow = t >> 2;                               // 0..63
  const int gcol = (((t & 3) ^ ((srow >> 1) & 3)) << 3); // swizzled col (shorts)
  const unsigned short* gA0 = A  + (size_t)(m0 + srow) * 1024 + gcol;
  const unsigned short* gA1 = gA0 + (size_t)64 * 1024;
  const unsigned short* gB0 = Bm + (size_t)(n0 + srow) * 1024 + gcol;
  const unsigned short* gB1 = gB0 + (size_t)64 * 1024;

  const int rc = (quad ^ ((lrow >> 1) & 3)) << 3;        // shorts

  f32x4 acc[4][4];
#pragma unroll
  for (int i = 0; i < 4; ++i)
#pragma unroll
    for (int j = 0; j < 4; ++j) acc[i][j] = (f32x4){0.f, 0.f, 0.f, 0.f};

  for (int k0 = 0; k0 < 1024; k0 += 32) {
    async16(&As[t * 8],        gA0 + k0);
    async16(&As[2048 + t * 8], gA1 + k0);
    async16(&Bs[t * 8],        gB0 + k0);
    async16(&Bs[2048 + t * 8], gB1 + k0);
    __syncthreads();

    bf16x8 af[4], bfr[4];
#pragma unroll
    for (int i = 0; i < 4; ++i)
      af[i] = *(const bf16x8*)&As[(wm + i * 16 + lrow) * 32 + rc];
#pragma unroll
    for (int j = 0; j < 4; ++j)
      bfr[j] = *(const bf16x8*)&Bs[(wn + j * 16 + lrow) * 32 + rc];
#pragma unroll
    for (int i = 0; i < 4; ++i)
#pragma unroll
      for (int j = 0; j < 4; ++j)
        acc[i][j] = __builtin_amdgcn_mfma_f32_16x16x32_bf16(af[i], bfr[j], acc[i][j], 0, 0, 0);
    __syncthreads();
  }

#pragma unroll
  for (int i = 0; i < 4; ++i) {
    const int mb = m0 + wm + i * 16 + quad * 4;
#pragma unroll
    for (int r = 0; r < 4; ++r) {
      const float bv = bias[mb + r];
#pragma unroll
      for (int j = 0; j < 4; ++j) {
        const int n = n0 + wn + j * 16 + lrow;
        qT[(size_t)(mb + r) * 16384 + n] = f2bf(acc[i][j][r] + bv);
      }
    }
  }
}

// ------- fallback gemm_q (fused fp32->bf16 inline), used if ws too small -------
__global__ __launch_bounds__(256) void gemm_q_fused(
    const float* __restrict__ Wq, const float* __restrict__ V,
    const float* __restrict__ bias, unsigned short* __restrict__ qT)
{
  __shared__ unsigned short As[BM * 32];
  __shared__ unsigned short Bs[BN * 32];

  const int m0 = blockIdx.y * BM;
  const int n0 = blockIdx.x * BN;
  const int t    = threadIdx.x;
  const int lane = t & 63;
  const int wave = t >> 6;
  const int wm = (wave >> 1) * 64;
  const int wn = (wave & 1) * 64;
  const int quad = lane >> 4;
  const int lrow = lane & 15;

  const int sr = t >> 1;
  const int sc = (t & 1) << 4;
  const float* gA = Wq + (size_t)(m0 + sr) * 1024 + sc;
  const float* gB = V  + (size_t)(n0 + sr) * 1024 + sc;

  f32x4 acc[4][4];
#pragma unroll
  for (int i = 0; i < 4; ++i)
#pragma unroll
    for (int j = 0; j < 4; ++j) acc[i][j] = (f32x4){0.f, 0.f, 0.f, 0.f};

  for (int k0 = 0; k0 < 1024; k0 += 32) {
    const float4* a4 = (const float4*)(gA + k0);
    const float4* b4 = (const float4*)(gB + k0);
    float4 av0 = a4[0], av1 = a4[1], av2 = a4[2], av3 = a4[3];
    float4 bv0 = b4[0], bv1 = b4[1], bv2 = b4[2], bv3 = b4[3];
    *(u16x8*)&As[sr * 32 + sc]     = pack8(av0, av1);
    *(u16x8*)&As[sr * 32 + sc + 8] = pack8(av2, av3);
    *(u16x8*)&Bs[sr * 32 + sc]     = pack8(bv0, bv1);
    *(u16x8*)&Bs[sr * 32 + sc + 8] = pack8(bv2, bv3);
    __syncthreads();

    bf16x8 af[4], bfr[4];
#pragma unroll
    for (int i = 0; i < 4; ++i)
      af[i] = *(const bf16x8*)&As[(wm + i * 16 + lrow) * 32 + quad * 8];
#pragma unroll
    for (int j = 0; j < 4; ++j)
      bfr[j] = *(const bf16x8*)&Bs[(wn + j * 16 + lrow) * 32 + quad * 8];
#pragma unroll
    for (int i = 0; i < 4; ++i)
#pragma unroll
      for (int j = 0; j < 4; ++j)
        acc[i][j] = __builtin_amdgcn_mfma_f32_16x16x32_bf16(af[i], bfr[j], acc[i][j], 0, 0, 0);
    __syncthreads();
  }

#pragma unroll
  for (int i = 0; i < 4; ++i) {
    const int mb = m0 + wm + i * 16 + quad * 4;
#pragma unroll
    for (int r = 0; r < 4; ++r) {
      const float bv = bias[mb + r];
#pragma unroll
      for (int j = 0; j < 4; ++j) {
        const int n = n0 + wn + j * 16 + lrow;
        qT[(size_t)(mb + r) * 16384 + n] = f2bf(acc[i][j][r] + bv);
      }
    }
  }
}

// ---------------- syrk_dot: symmetric, LDS BK=64, fused relu+dot ----------------
// job blockIdx.x in [0,36): tile pair (tx,ty) with ty<=tx. Diagonal: row-pass only.
__global__ __launch_bounds__(256) void syrk_dot(
    const unsigned short* __restrict__ qT, const float* __restrict__ W,
    float* __restrict__ out)
{
  __shared__ unsigned short As[BM * 64];
  __shared__ unsigned short Bs[BN * 64];

  const int bb = blockIdx.z;
  const int job = blockIdx.x;
  int tx = 0;
  while ((tx + 1) * (tx + 2) / 2 <= job) ++tx;
  const int ty = job - tx * (tx + 1) / 2;
  const int x0 = tx * BM;
  const int y0 = ty * BN;
  const bool diag = (tx == ty);

  const int t    = threadIdx.x;
  const int lane = t & 63;
  const int wave = t >> 6;
  const int wm = (wave >> 1) * 64;
  const int wn = (wave & 1) * 64;
  const int quad = lane >> 4;
  const int lrow = lane & 15;

  // staging: issue p covers rows p*32 + (t>>3); global chunk XOR-swizzled
  const int srow = t >> 3;                              // 0..31
  const int gcol = (((t & 7) ^ (srow & 7)) << 3);       // shorts
  const size_t cbase = (size_t)bb * 2048 + gcol;
  const unsigned short* gA = qT + (size_t)(x0 + srow) * 16384 + cbase;
  const unsigned short* gB = qT + (size_t)(y0 + srow) * 16384 + cbase;

  f32x4 acc[4][4];
#pragma unroll
  for (int i = 0; i < 4; ++i)
#pragma unroll
    for (int j = 0; j < 4; ++j) acc[i][j] = (f32x4){0.f, 0.f, 0.f, 0.f};

  for (int k0 = 0; k0 < 2048; k0 += 64) {
#pragma unroll
    for (int p = 0; p < 4; ++p) {
      async16(&As[p * 2048 + t * 8], gA + (size_t)p * 32 * 16384 + k0);
      async16(&Bs[p * 2048 + t * 8], gB + (size_t)p * 32 * 16384 + k0);
    }
    __syncthreads();

#pragma unroll
    for (int kk = 0; kk < 2; ++kk) {
      const int rc = (((kk * 4 + quad) ^ (lrow & 7)) << 3);  // shorts
      bf16x8 af[4], bfr[4];
#pragma unroll
      for (int i = 0; i < 4; ++i)
        af[i] = *(const bf16x8*)&As[(wm + i * 16 + lrow) * 64 + rc];
#pragma unroll
      for (int j = 0; j < 4; ++j)
        bfr[j] = *(const bf16x8*)&Bs[(wn + j * 16 + lrow) * 64 + rc];
#pragma unroll
      for (int i = 0; i < 4; ++i)
#pragma unroll
        for (int j = 0; j < 4; ++j)
          acc[i][j] = __builtin_amdgcn_mfma_f32_16x16x32_bf16(af[i], bfr[j], acc[i][j], 0, 0, 0);
    }
    __syncthreads();
  }

  float* ob = out + bb * 1024;

  // row pass: out[x] += sum_y relu(C[x,y]) * W[y]
  float wv[4];
#pragma unroll
  for (int j = 0; j < 4; ++j) wv[j] = W[y0 + wn + j * 16 + lrow];

#pragma unroll
  for (int i = 0; i < 4; ++i) {
#pragma unroll
    for (int r = 0; r < 4; ++r) {
      float p = 0.f;
#pragma unroll
      for (int j = 0; j < 4; ++j) {
        float v = acc[i][j][r];
        v = v > 0.f ? v : 0.f;
        p += v * wv[j];
      }
#pragma unroll
      for (int off = 1; off < 16; off <<= 1) p += __shfl_xor(p, off, 64);
      if (lrow == 0)
        atomicAdd(&ob[x0 + wm + i * 16 + quad * 4 + r], p);
    }
  }

  // col pass (off-diagonal only): out[y] += sum_x relu(C[x,y]) * W[x]
  if (!diag) {
    float wx[4][4];
#pragma unroll
    for (int i = 0; i < 4; ++i)
#pragma unroll
      for (int r = 0; r < 4; ++r)
        wx[i][r] = W[x0 + wm + i * 16 + quad * 4 + r];

#pragma unroll
    for (int j = 0; j < 4; ++j) {
      float pc = 0.f;
#pragma unroll
      for (int i = 0; i < 4; ++i)
#pragma unroll
        for (int r = 0; r < 4; ++r) {
          float v = acc[i][j][r];
          v = v > 0.f ? v : 0.f;
          pc += v * wx[i][r];
        }
      pc += __shfl_xor(pc, 16, 64);
      pc += __shfl_xor(pc, 32, 64);
      if (quad == 0)
        atomicAdd(&ob[y0 + wn + j * 16 + lrow], pc);
    }
  }
}

extern "C" void kernel_launch(void* const* d_in, const int* in_sizes, int n_in,
                              void* d_out, int out_size, void* d_ws, size_t ws_size,
                              hipStream_t stream) {
  const float* vec   = (const float*)d_in[0];  // [8,2048,1024]
  const float* wq_w  = (const float*)d_in[1];  // [1024,1024]
  const float* wq_b  = (const float*)d_in[2];  // [1024]
  const float* lin_w = (const float*)d_in[3];  // [1,1024]
  const float* lin_b = (const float*)d_in[4];  // [1]
  float* out = (float*)d_out;                  // [8,1024]

  unsigned short* qT = (unsigned short*)d_ws;                    // 32 MiB
  const size_t need = (size_t)(32 + 32 + 2) * 1024 * 1024;

  if (ws_size >= need) {
    unsigned short* vecbf = qT + (size_t)16 * 1024 * 1024;       // 32 MiB
    unsigned short* wqbf  = vecbf + (size_t)16 * 1024 * 1024;    // 2 MiB
    prep<<<dim3(8192 + 512), dim3(256), 0, stream>>>(vec, vecbf, wq_w, wqbf, lin_b, out);
    gemm_q<<<dim3(128, 8), dim3(256), 0, stream>>>(wqbf, vecbf, wq_b, qT);
  } else {
    init_out<<<dim3(32), dim3(256), 0, stream>>>(out, lin_b);
    gemm_q_fused<<<dim3(128, 8), dim3(256), 0, stream>>>(wq_w, vec, wq_b, qT);
  }
  syrk_dot<<<dim3(36, 1, 8), dim3(256), 0, stream>>>(qT, lin_w, out);
}